// Round 21
// baseline (1728.095 us; speedup 1.0000x reference)
//
#include <hip/hip_runtime.h>

// GNODecoder round 21: r20 falsified the batch-duty theory (2-edge/lane
// regressed; lgkmcnt shared between ds_read and s_load defeats scalar
// prefetch structurally). Edge-kernel family plateaued -> REVERT fused to
// r19 exactly (proven best, 1130 us). Attack the remaining 374 us:
// proj_kernel's P0 reads are wave-uniform but 1KB-strided (128 scattered
// s_load_dwordx8 per 1024 FMAs, sL1-missing). Fix: transpose P0 -> P0T
// [256][128] in ws (~10 us kernel); proj reads are then consecutive-in-i
// s_load_dwordx16 bursts (1 load : 16 FMAs, prefetchable).

#define BLOCK 256

#define OFF_HT   0      // [64][68] m-major, 4352 floats
#define OFF_SACC 4352   // [QB*129]

__device__ __forceinline__ float gelu_f(float x) {
    // jax.nn.gelu default (approximate=True, tanh form)
    float x3 = x * x * x;
    float t  = 0.7978845608028654f * fmaf(0.044715f, x3, x);
    float e  = __expf(2.0f * t);
    float r  = __builtin_amdgcn_rcpf(e + 1.0f);
    return 0.5f * x * (1.0f + (1.0f - 2.0f * r));
}

// ---------- sort machinery (proven) ----------

__global__ void hist_kernel(const int* __restrict__ dst, int* __restrict__ hist, int E) {
    int e = blockIdx.x * blockDim.x + threadIdx.x;
    if (e < E) atomicAdd(&hist[dst[e]], 1);
}

__global__ __launch_bounds__(1024) void scan_kernel(const int* __restrict__ hist,
                                                    int* __restrict__ start, int n) {
    __shared__ int wsum[16];
    __shared__ int woff[16];
    int tid = threadIdx.x;
    int lane = tid & 63, wid = tid >> 6;
    int carry = 0;  // meaningful on tid 0 only
    for (int base = 0; base < n; base += 1024) {
        int i = base + tid;
        int v = (i < n) ? hist[i] : 0;
        int incl = v;
#pragma unroll
        for (int off = 1; off < 64; off <<= 1) {
            int t = __shfl_up(incl, off, 64);
            if (lane >= off) incl += t;
        }
        if (lane == 63) wsum[wid] = incl;
        __syncthreads();
        if (tid == 0) {
            int acc = carry;
#pragma unroll
            for (int w = 0; w < 16; ++w) { woff[w] = acc; acc += wsum[w]; }
            carry = acc;
        }
        __syncthreads();
        if (i < n) start[i] = woff[wid] + incl - v;
        __syncthreads();
    }
    if (threadIdx.x == 0) start[n] = carry;
}

__global__ void scatter_kernel(const int* __restrict__ dst, const int* __restrict__ src,
                               const int* __restrict__ start, int* __restrict__ cursor,
                               int* __restrict__ dsts, int* __restrict__ srcs, int E) {
    int e = blockIdx.x * blockDim.x + threadIdx.x;
    if (e >= E) return;
    int d = dst[e];
    int pos = start[d] + atomicAdd(&cursor[d], 1);
    dsts[pos] = d;
    srcs[pos] = src[e];
}

// ---------- P0 transpose: [128][256] -> [256][128] ----------

__global__ void transpose_kernel(const float* __restrict__ P0, float* __restrict__ P0T) {
    int idx = blockIdx.x * blockDim.x + threadIdx.x;  // 32768 elements
    if (idx < 128 * 256) {
        int r = idx >> 8, c = idx & 255;
        P0T[c * 128 + r] = P0[idx];
    }
}

// ---------- fused: lane-per-edge, wave-per-n-slice, B via scalar pipe (r19) ----------

template <int QB, bool FUSED_PROJ>
__global__ __launch_bounds__(BLOCK) void fused_kernel(
    const float* __restrict__ rndata,   // [NL,128]
    const float* __restrict__ qpos,     // [NQ,3]
    const float* __restrict__ lpos,     // [NL,3]
    const int*   __restrict__ dsts,     // [E] sorted by dst
    const int*   __restrict__ srcs,     // [E]
    const int*   __restrict__ start,    // [NQ+1]
    const float* __restrict__ W0, const float* __restrict__ b0,
    const float* __restrict__ W1, const float* __restrict__ b1,
    const float* __restrict__ W2, const float* __restrict__ b2,
    const float* __restrict__ P0, const float* __restrict__ pb0,
    const float* __restrict__ P1, const float* __restrict__ pb1,
    float* __restrict__ agg,            // [NQ,128] mean (path A)
    float* __restrict__ out,            // [NQ,4]   (FUSED_PROJ)
    int nq)
{
    extern __shared__ float smem[];
    const int tid = threadIdx.x;
    float* hT   = smem + OFF_HT;    // [64][68] row m = edge-lane, cols = h channels
    float* sacc = smem + OFF_SACC;  // [QB][129]

    for (int i = tid; i < QB * 129; i += BLOCK) sacc[i] = 0.f;

    const int q0   = blockIdx.x * QB;
    const int qend = min(q0 + QB, nq);
    const int e0 = start[q0], e1 = start[qend];
    const int ntiles = (e1 - e0 + 63) >> 6;

    const int m  = tid & 63;                                    // edge row
    const int wn1 = __builtin_amdgcn_readfirstlane((tid >> 6) * 16);  // L0/L1 n-slice
    const int wn2 = __builtin_amdgcn_readfirstlane((tid >> 6) * 32);  // L2 n-slice

    for (int t = 0; t < ntiles; ++t) {
        const int ebase = e0 + (t << 6);
        int  e     = ebase + m;
        bool valid = e < e1;
        int  d = valid ? dsts[e] : q0;
        int  s = valid ? srcs[e] : 0;
        float pin[6];
        {
            const float* pq = qpos + d * 3;
            pin[0] = pq[0]; pin[1] = pq[1]; pin[2] = pq[2];
            const float* pl = lpos + s * 3;
            pin[3] = pl[0]; pin[4] = pl[1]; pin[5] = pl[2];
        }

        // ---- L0: h0[m][wn1..wn1+16) ; B = W0 via s_load ----
        float C0[16];
#pragma unroll
        for (int j = 0; j < 16; ++j) C0[j] = b0[wn1 + j];
#pragma unroll
        for (int k = 0; k < 6; ++k) {
            float a = pin[k];
#pragma unroll
            for (int j = 0; j < 16; ++j)
                C0[j] = fmaf(a, W0[k * 64 + wn1 + j], C0[j]);
        }
        __syncthreads();  // prev tile's L2 reads done (t==0: sacc init visible)
#pragma unroll
        for (int j4 = 0; j4 < 4; ++j4) {
            float4 o = make_float4(gelu_f(C0[4 * j4 + 0]), gelu_f(C0[4 * j4 + 1]),
                                   gelu_f(C0[4 * j4 + 2]), gelu_f(C0[4 * j4 + 3]));
            *(float4*)(hT + m * 68 + wn1 + 4 * j4) = o;
        }
        __syncthreads();  // h0 ready

        // ---- L1: C1[16] over k=0..63 ; A = hT[m][k] (own row), B = W1 s_load ----
        float C1[16];
#pragma unroll
        for (int j = 0; j < 16; ++j) C1[j] = b1[wn1 + j];
#pragma unroll 2
        for (int k4 = 0; k4 < 16; ++k4) {
            float4 a4 = *(const float4*)(hT + m * 68 + k4 * 4);
            float av[4] = {a4.x, a4.y, a4.z, a4.w};
#pragma unroll
            for (int kk = 0; kk < 4; ++kk) {
                float a = av[kk];
#pragma unroll
                for (int j = 0; j < 16; ++j)
                    C1[j] = fmaf(a, W1[(k4 * 4 + kk) * 64 + wn1 + j], C1[j]);
            }
        }
        __syncthreads();  // all h0 reads done
#pragma unroll
        for (int j4 = 0; j4 < 4; ++j4) {
            float4 o = make_float4(gelu_f(C1[4 * j4 + 0]), gelu_f(C1[4 * j4 + 1]),
                                   gelu_f(C1[4 * j4 + 2]), gelu_f(C1[4 * j4 + 3]));
            *(float4*)(hT + m * 68 + wn1 + 4 * j4) = o;
        }
        __syncthreads();  // h1 ready

        // ---- L2: C2[32] over k=0..63 ; B = W2 s_load ; epilogue ds_add ----
        float C2[32];
#pragma unroll
        for (int j = 0; j < 32; ++j) C2[j] = b2[wn2 + j];
#pragma unroll 2
        for (int k4 = 0; k4 < 16; ++k4) {
            float4 a4 = *(const float4*)(hT + m * 68 + k4 * 4);
            float av[4] = {a4.x, a4.y, a4.z, a4.w};
#pragma unroll
            for (int kk = 0; kk < 4; ++kk) {
                float a = av[kk];
#pragma unroll
                for (int j = 0; j < 32; ++j)
                    C2[j] = fmaf(a, W2[(k4 * 4 + kk) * 128 + wn2 + j], C2[j]);
            }
        }
        if (valid) {
            const float* r  = rndata + (size_t)s * 128 + wn2;
            float*       ac = &sacc[(d - q0) * 129 + wn2];
#pragma unroll
            for (int j4 = 0; j4 < 8; ++j4) {
                float4 rv = *(const float4*)(r + 4 * j4);
                atomicAdd(&ac[4 * j4 + 0], C2[4 * j4 + 0] * rv.x);
                atomicAdd(&ac[4 * j4 + 1], C2[4 * j4 + 1] * rv.y);
                atomicAdd(&ac[4 * j4 + 2], C2[4 * j4 + 2] * rv.z);
                atomicAdd(&ac[4 * j4 + 3], C2[4 * j4 + 3] * rv.w);
            }
        }
        // next iteration's first barrier orders these L2 reads/ds_adds
    }
    __syncthreads();  // last tile's ds_adds visible (and ntiles==0 init path)

    if (!FUSED_PROJ) {
        // write per-query mean to global agg (coalesced across c)
        for (int idx = tid; idx < QB * 128; idx += BLOCK) {
            int ql = idx >> 7, c = idx & 127;
            int q  = q0 + ql;
            if (q < qend) {
                float deg = (float)(start[q + 1] - start[q]);
                agg[(size_t)q * 128 + c] = sacc[ql * 129 + c] / fmaxf(deg, 1.f);
            }
        }
    } else {
        if (tid < QB) {
            int q = q0 + tid;
            if (q < nq) {
                float deg = (float)(start[q + 1] - start[q]);
                float inv = 1.0f / fmaxf(deg, 1.f);
                const float* aq = &sacc[tid * 129];
                float o0 = pb1[0], o1 = pb1[1], o2 = pb1[2], o3 = pb1[3];
#pragma unroll 1
                for (int jj = 0; jj < 256; jj += 8) {
                    float acc[8];
#pragma unroll
                    for (int u = 0; u < 8; ++u) acc[u] = pb0[jj + u];
#pragma unroll
                    for (int i = 0; i < 128; ++i) {
                        float av = aq[i] * inv;
#pragma unroll
                        for (int u = 0; u < 8; ++u)
                            acc[u] = fmaf(av, P0[i * 256 + jj + u], acc[u]);
                    }
#pragma unroll
                    for (int u = 0; u < 8; ++u) {
                        float h = gelu_f(acc[u]);
                        o0 = fmaf(h, P1[(jj + u) * 4 + 0], o0);
                        o1 = fmaf(h, P1[(jj + u) * 4 + 1], o1);
                        o2 = fmaf(h, P1[(jj + u) * 4 + 2], o2);
                        o3 = fmaf(h, P1[(jj + u) * 4 + 3], o3);
                    }
                }
                float4* o4 = (float4*)(out + (size_t)q * 4);
                *o4 = make_float4(o0, o1, o2, o3);
            }
        }
    }
}

// ---------- projection: transposed-P0 scalar streaming ----------

__global__ __launch_bounds__(256) void proj_t_kernel(
    const float* __restrict__ agg,      // [NQ,128] mean
    const float* __restrict__ P0T,      // [256][128] transposed
    const float* __restrict__ pb0,
    const float* __restrict__ P1, const float* __restrict__ pb1,
    float* __restrict__ out, int nq)
{
    int q = blockIdx.x * blockDim.x + threadIdx.x;
    if (q >= nq) return;

    float a[128];
    const float4* ag4 = (const float4*)(agg + (size_t)q * 128);
#pragma unroll
    for (int i = 0; i < 32; ++i) {
        float4 v = ag4[i];
        a[4 * i + 0] = v.x; a[4 * i + 1] = v.y;
        a[4 * i + 2] = v.z; a[4 * i + 3] = v.w;
    }

    float o0 = pb1[0], o1 = pb1[1], o2 = pb1[2], o3 = pb1[3];
#pragma unroll 1
    for (int jj = 0; jj < 256; jj += 8) {
        float acc[8];
#pragma unroll
        for (int u = 0; u < 8; ++u) acc[u] = pb0[jj + u];
#pragma unroll 4
        for (int i = 0; i < 128; ++i) {
            float av = a[i];
#pragma unroll
            for (int u = 0; u < 8; ++u)
                acc[u] = fmaf(av, P0T[(jj + u) * 128 + i], acc[u]);
        }
#pragma unroll
        for (int u = 0; u < 8; ++u) {
            float h = gelu_f(acc[u]);
            o0 = fmaf(h, P1[(jj + u) * 4 + 0], o0);
            o1 = fmaf(h, P1[(jj + u) * 4 + 1], o1);
            o2 = fmaf(h, P1[(jj + u) * 4 + 2], o2);
            o3 = fmaf(h, P1[(jj + u) * 4 + 3], o3);
        }
    }
    float4* o4 = (float4*)(out + (size_t)q * 4);
    *o4 = make_float4(o0, o1, o2, o3);
}

extern "C" void kernel_launch(void* const* d_in, const int* in_sizes, int n_in,
                              void* d_out, int out_size, void* d_ws, size_t ws_size,
                              hipStream_t stream)
{
    const float* rndata = (const float*)d_in[0];
    const float* qpos   = (const float*)d_in[1];
    const float* lpos   = (const float*)d_in[2];
    const int*   dst    = (const int*)d_in[3];
    const int*   src    = (const int*)d_in[4];
    const float* W0  = (const float*)d_in[5];
    const float* b0  = (const float*)d_in[6];
    const float* W1  = (const float*)d_in[7];
    const float* b1  = (const float*)d_in[8];
    const float* W2  = (const float*)d_in[9];
    const float* b2  = (const float*)d_in[10];
    const float* P0  = (const float*)d_in[11];
    const float* pb0 = (const float*)d_in[12];
    const float* P1  = (const float*)d_in[13];
    const float* pb1 = (const float*)d_in[14];

    int nq = in_sizes[1] / 3;
    int E  = in_sizes[3];

    // ws layout: [agg nq*128 (path A)] [hist] [cursor] [start] [dsts] [srcs] [P0T]
    size_t agg_bytes  = (size_t)nq * 128 * sizeof(float);
    size_t p0t_bytes  = 128 * 256 * sizeof(float);
    size_t sort_bytes = 0;
    {
        size_t o = 0;
        o += ((size_t)nq * sizeof(int) + 15) & ~(size_t)15;
        o += ((size_t)nq * sizeof(int) + 15) & ~(size_t)15;
        o += ((size_t)(nq + 1) * sizeof(int) + 15) & ~(size_t)15;
        o += ((size_t)E * sizeof(int) + 15) & ~(size_t)15;
        o += ((size_t)E * sizeof(int) + 15) & ~(size_t)15;
        sort_bytes = o;
    }
    bool path_a = (agg_bytes + sort_bytes + p0t_bytes) <= ws_size;

    size_t off = path_a ? agg_bytes : 0;
    auto alloc = [&](size_t bytes) {
        void* p = (char*)d_ws + off;
        off += (bytes + 15) & ~(size_t)15;
        return p;
    };
    float* agg   = (float*)d_ws;  // path A only
    int* hist    = (int*)alloc((size_t)nq * sizeof(int));
    int* cursor  = (int*)alloc((size_t)nq * sizeof(int));
    int* start   = (int*)alloc((size_t)(nq + 1) * sizeof(int));
    int* dsts    = (int*)alloc((size_t)E * sizeof(int));
    int* srcs    = (int*)alloc((size_t)E * sizeof(int));
    float* p0t   = (float*)alloc(p0t_bytes);  // path A only

    size_t histpad = ((size_t)nq * sizeof(int) + 15) & ~(size_t)15;
    hipMemsetAsync(hist, 0, 2 * histpad, stream);

    hist_kernel<<<(E + 255) / 256, 256, 0, stream>>>(dst, hist, E);
    scan_kernel<<<1, 1024, 0, stream>>>(hist, start, nq);
    scatter_kernel<<<(E + 255) / 256, 256, 0, stream>>>(dst, src, start, cursor, dsts, srcs, E);

    constexpr int    QB   = 24;
    constexpr size_t SMEM = (size_t)(4352 + QB * 129) * 4;  // 29,792 B -> 5 blocks/CU
    int nb = (nq + QB - 1) / QB;

    if (path_a) {
        transpose_kernel<<<128, 256, 0, stream>>>(P0, p0t);
        fused_kernel<QB, false><<<nb, BLOCK, SMEM, stream>>>(
            rndata, qpos, lpos, dsts, srcs, start,
            W0, b0, W1, b1, W2, b2, P0, pb0, P1, pb1, agg, nullptr, nq);
        proj_t_kernel<<<(nq + 255) / 256, 256, 0, stream>>>(
            agg, p0t, pb0, P1, pb1, (float*)d_out, nq);
    } else {
        fused_kernel<QB, true><<<nb, BLOCK, SMEM, stream>>>(
            rndata, qpos, lpos, dsts, srcs, start,
            W0, b0, W1, b1, W2, b2, P0, pb0, P1, pb1, nullptr, (float*)d_out, nq);
    }
}

// Round 22
// 1497.738 us; speedup vs baseline: 1.1538x; 1.1538x over previous
//
#include <hip/hip_runtime.h>

// GNODecoder round 22: REVERT to the r19 configuration exactly -- proven
// session best (1504 us total: fused 1130 + plain proj ~270 + sort ~100).
// r21's P0-transpose proj regressed ~200 us (8 strided streams beat by the
// original consecutive s_load_dwordx8 pattern) -> plain proj restored.
// Ledger: 8 edge-kernel structures all land 1.13-1.35 ms, VALUBusy 21-26%;
// the stall is shared-lgkmcnt serialization of ds_read(A) vs s_load(B).

#define BLOCK 256

#define OFF_HT   0      // [64][68] m-major, 4352 floats
#define OFF_SACC 4352   // [QB*129]

__device__ __forceinline__ float gelu_f(float x) {
    // jax.nn.gelu default (approximate=True, tanh form)
    float x3 = x * x * x;
    float t  = 0.7978845608028654f * fmaf(0.044715f, x3, x);
    float e  = __expf(2.0f * t);
    float r  = __builtin_amdgcn_rcpf(e + 1.0f);
    return 0.5f * x * (1.0f + (1.0f - 2.0f * r));
}

// ---------- sort machinery (proven) ----------

__global__ void hist_kernel(const int* __restrict__ dst, int* __restrict__ hist, int E) {
    int e = blockIdx.x * blockDim.x + threadIdx.x;
    if (e < E) atomicAdd(&hist[dst[e]], 1);
}

__global__ __launch_bounds__(1024) void scan_kernel(const int* __restrict__ hist,
                                                    int* __restrict__ start, int n) {
    __shared__ int wsum[16];
    __shared__ int woff[16];
    int tid = threadIdx.x;
    int lane = tid & 63, wid = tid >> 6;
    int carry = 0;  // meaningful on tid 0 only
    for (int base = 0; base < n; base += 1024) {
        int i = base + tid;
        int v = (i < n) ? hist[i] : 0;
        int incl = v;
#pragma unroll
        for (int off = 1; off < 64; off <<= 1) {
            int t = __shfl_up(incl, off, 64);
            if (lane >= off) incl += t;
        }
        if (lane == 63) wsum[wid] = incl;
        __syncthreads();
        if (tid == 0) {
            int acc = carry;
#pragma unroll
            for (int w = 0; w < 16; ++w) { woff[w] = acc; acc += wsum[w]; }
            carry = acc;
        }
        __syncthreads();
        if (i < n) start[i] = woff[wid] + incl - v;
        __syncthreads();
    }
    if (threadIdx.x == 0) start[n] = carry;
}

__global__ void scatter_kernel(const int* __restrict__ dst, const int* __restrict__ src,
                               const int* __restrict__ start, int* __restrict__ cursor,
                               int* __restrict__ dsts, int* __restrict__ srcs, int E) {
    int e = blockIdx.x * blockDim.x + threadIdx.x;
    if (e >= E) return;
    int d = dst[e];
    int pos = start[d] + atomicAdd(&cursor[d], 1);
    dsts[pos] = d;
    srcs[pos] = src[e];
}

// ---------- fused: lane-per-edge, wave-per-n-slice, B via scalar pipe ----------

template <int QB, bool FUSED_PROJ>
__global__ __launch_bounds__(BLOCK) void fused_kernel(
    const float* __restrict__ rndata,   // [NL,128]
    const float* __restrict__ qpos,     // [NQ,3]
    const float* __restrict__ lpos,     // [NL,3]
    const int*   __restrict__ dsts,     // [E] sorted by dst
    const int*   __restrict__ srcs,     // [E]
    const int*   __restrict__ start,    // [NQ+1]
    const float* __restrict__ W0, const float* __restrict__ b0,
    const float* __restrict__ W1, const float* __restrict__ b1,
    const float* __restrict__ W2, const float* __restrict__ b2,
    const float* __restrict__ P0, const float* __restrict__ pb0,
    const float* __restrict__ P1, const float* __restrict__ pb1,
    float* __restrict__ agg,            // [NQ,128] mean (path A)
    float* __restrict__ out,            // [NQ,4]   (FUSED_PROJ)
    int nq)
{
    extern __shared__ float smem[];
    const int tid = threadIdx.x;
    float* hT   = smem + OFF_HT;    // [64][68] row m = edge-lane, cols = h channels
    float* sacc = smem + OFF_SACC;  // [QB][129]

    for (int i = tid; i < QB * 129; i += BLOCK) sacc[i] = 0.f;

    const int q0   = blockIdx.x * QB;
    const int qend = min(q0 + QB, nq);
    const int e0 = start[q0], e1 = start[qend];
    const int ntiles = (e1 - e0 + 63) >> 6;

    const int m  = tid & 63;                                    // edge row
    const int wn1 = __builtin_amdgcn_readfirstlane((tid >> 6) * 16);  // L0/L1 n-slice
    const int wn2 = __builtin_amdgcn_readfirstlane((tid >> 6) * 32);  // L2 n-slice

    for (int t = 0; t < ntiles; ++t) {
        const int ebase = e0 + (t << 6);
        int  e     = ebase + m;
        bool valid = e < e1;
        int  d = valid ? dsts[e] : q0;
        int  s = valid ? srcs[e] : 0;
        float pin[6];
        {
            const float* pq = qpos + d * 3;
            pin[0] = pq[0]; pin[1] = pq[1]; pin[2] = pq[2];
            const float* pl = lpos + s * 3;
            pin[3] = pl[0]; pin[4] = pl[1]; pin[5] = pl[2];
        }

        // ---- L0: h0[m][wn1..wn1+16) ; B = W0 via s_load ----
        float C0[16];
#pragma unroll
        for (int j = 0; j < 16; ++j) C0[j] = b0[wn1 + j];
#pragma unroll
        for (int k = 0; k < 6; ++k) {
            float a = pin[k];
#pragma unroll
            for (int j = 0; j < 16; ++j)
                C0[j] = fmaf(a, W0[k * 64 + wn1 + j], C0[j]);
        }
        __syncthreads();  // prev tile's L2 reads done (t==0: sacc init visible)
#pragma unroll
        for (int j4 = 0; j4 < 4; ++j4) {
            float4 o = make_float4(gelu_f(C0[4 * j4 + 0]), gelu_f(C0[4 * j4 + 1]),
                                   gelu_f(C0[4 * j4 + 2]), gelu_f(C0[4 * j4 + 3]));
            *(float4*)(hT + m * 68 + wn1 + 4 * j4) = o;
        }
        __syncthreads();  // h0 ready

        // ---- L1: C1[16] over k=0..63 ; A = hT[m][k] (own row), B = W1 s_load ----
        float C1[16];
#pragma unroll
        for (int j = 0; j < 16; ++j) C1[j] = b1[wn1 + j];
#pragma unroll 2
        for (int k4 = 0; k4 < 16; ++k4) {
            float4 a4 = *(const float4*)(hT + m * 68 + k4 * 4);
            float av[4] = {a4.x, a4.y, a4.z, a4.w};
#pragma unroll
            for (int kk = 0; kk < 4; ++kk) {
                float a = av[kk];
#pragma unroll
                for (int j = 0; j < 16; ++j)
                    C1[j] = fmaf(a, W1[(k4 * 4 + kk) * 64 + wn1 + j], C1[j]);
            }
        }
        __syncthreads();  // all h0 reads done
#pragma unroll
        for (int j4 = 0; j4 < 4; ++j4) {
            float4 o = make_float4(gelu_f(C1[4 * j4 + 0]), gelu_f(C1[4 * j4 + 1]),
                                   gelu_f(C1[4 * j4 + 2]), gelu_f(C1[4 * j4 + 3]));
            *(float4*)(hT + m * 68 + wn1 + 4 * j4) = o;
        }
        __syncthreads();  // h1 ready

        // ---- L2: C2[32] over k=0..63 ; B = W2 s_load ; epilogue ds_add ----
        float C2[32];
#pragma unroll
        for (int j = 0; j < 32; ++j) C2[j] = b2[wn2 + j];
#pragma unroll 2
        for (int k4 = 0; k4 < 16; ++k4) {
            float4 a4 = *(const float4*)(hT + m * 68 + k4 * 4);
            float av[4] = {a4.x, a4.y, a4.z, a4.w};
#pragma unroll
            for (int kk = 0; kk < 4; ++kk) {
                float a = av[kk];
#pragma unroll
                for (int j = 0; j < 32; ++j)
                    C2[j] = fmaf(a, W2[(k4 * 4 + kk) * 128 + wn2 + j], C2[j]);
            }
        }
        if (valid) {
            const float* r  = rndata + (size_t)s * 128 + wn2;
            float*       ac = &sacc[(d - q0) * 129 + wn2];
#pragma unroll
            for (int j4 = 0; j4 < 8; ++j4) {
                float4 rv = *(const float4*)(r + 4 * j4);
                atomicAdd(&ac[4 * j4 + 0], C2[4 * j4 + 0] * rv.x);
                atomicAdd(&ac[4 * j4 + 1], C2[4 * j4 + 1] * rv.y);
                atomicAdd(&ac[4 * j4 + 2], C2[4 * j4 + 2] * rv.z);
                atomicAdd(&ac[4 * j4 + 3], C2[4 * j4 + 3] * rv.w);
            }
        }
        // next iteration's first barrier orders these L2 reads/ds_adds
    }
    __syncthreads();  // last tile's ds_adds visible (and ntiles==0 init path)

    if (!FUSED_PROJ) {
        // write per-query mean to global agg (coalesced across c)
        for (int idx = tid; idx < QB * 128; idx += BLOCK) {
            int ql = idx >> 7, c = idx & 127;
            int q  = q0 + ql;
            if (q < qend) {
                float deg = (float)(start[q + 1] - start[q]);
                agg[(size_t)q * 128 + c] = sacc[ql * 129 + c] / fmaxf(deg, 1.f);
            }
        }
    } else {
        if (tid < QB) {
            int q = q0 + tid;
            if (q < nq) {
                float deg = (float)(start[q + 1] - start[q]);
                float inv = 1.0f / fmaxf(deg, 1.f);
                const float* aq = &sacc[tid * 129];
                float o0 = pb1[0], o1 = pb1[1], o2 = pb1[2], o3 = pb1[3];
#pragma unroll 1
                for (int jj = 0; jj < 256; jj += 8) {
                    float acc[8];
#pragma unroll
                    for (int u = 0; u < 8; ++u) acc[u] = pb0[jj + u];
#pragma unroll
                    for (int i = 0; i < 128; ++i) {
                        float av = aq[i] * inv;
#pragma unroll
                        for (int u = 0; u < 8; ++u)
                            acc[u] = fmaf(av, P0[i * 256 + jj + u], acc[u]);
                    }
#pragma unroll
                    for (int u = 0; u < 8; ++u) {
                        float h = gelu_f(acc[u]);
                        o0 = fmaf(h, P1[(jj + u) * 4 + 0], o0);
                        o1 = fmaf(h, P1[(jj + u) * 4 + 1], o1);
                        o2 = fmaf(h, P1[(jj + u) * 4 + 2], o2);
                        o3 = fmaf(h, P1[(jj + u) * 4 + 3], o3);
                    }
                }
                float4* o4 = (float4*)(out + (size_t)q * 4);
                *o4 = make_float4(o0, o1, o2, o3);
            }
        }
    }
}

// ---------- projection: plain r7/r9 kernel (proven ~270 us) ----------

__global__ __launch_bounds__(256) void proj_kernel(
    const float* __restrict__ agg,      // [NQ,128] mean
    const float* __restrict__ P0, const float* __restrict__ pb0,
    const float* __restrict__ P1, const float* __restrict__ pb1,
    float* __restrict__ out, int nq)
{
    int q = blockIdx.x * blockDim.x + threadIdx.x;
    if (q >= nq) return;

    float a[128];
    const float4* ag4 = (const float4*)(agg + (size_t)q * 128);
#pragma unroll
    for (int i = 0; i < 32; ++i) {
        float4 v = ag4[i];
        a[4 * i + 0] = v.x; a[4 * i + 1] = v.y;
        a[4 * i + 2] = v.z; a[4 * i + 3] = v.w;
    }

    float o0 = pb1[0], o1 = pb1[1], o2 = pb1[2], o3 = pb1[3];
#pragma unroll 1
    for (int jj = 0; jj < 256; jj += 8) {
        float acc[8];
#pragma unroll
        for (int u = 0; u < 8; ++u) acc[u] = pb0[jj + u];
#pragma unroll
        for (int i = 0; i < 128; ++i) {
            float av = a[i];
#pragma unroll
            for (int u = 0; u < 8; ++u)
                acc[u] = fmaf(av, P0[i * 256 + jj + u], acc[u]);
        }
#pragma unroll
        for (int u = 0; u < 8; ++u) {
            float h = gelu_f(acc[u]);
            o0 = fmaf(h, P1[(jj + u) * 4 + 0], o0);
            o1 = fmaf(h, P1[(jj + u) * 4 + 1], o1);
            o2 = fmaf(h, P1[(jj + u) * 4 + 2], o2);
            o3 = fmaf(h, P1[(jj + u) * 4 + 3], o3);
        }
    }
    float4* o4 = (float4*)(out + (size_t)q * 4);
    *o4 = make_float4(o0, o1, o2, o3);
}

extern "C" void kernel_launch(void* const* d_in, const int* in_sizes, int n_in,
                              void* d_out, int out_size, void* d_ws, size_t ws_size,
                              hipStream_t stream)
{
    const float* rndata = (const float*)d_in[0];
    const float* qpos   = (const float*)d_in[1];
    const float* lpos   = (const float*)d_in[2];
    const int*   dst    = (const int*)d_in[3];
    const int*   src    = (const int*)d_in[4];
    const float* W0  = (const float*)d_in[5];
    const float* b0  = (const float*)d_in[6];
    const float* W1  = (const float*)d_in[7];
    const float* b1  = (const float*)d_in[8];
    const float* W2  = (const float*)d_in[9];
    const float* b2  = (const float*)d_in[10];
    const float* P0  = (const float*)d_in[11];
    const float* pb0 = (const float*)d_in[12];
    const float* P1  = (const float*)d_in[13];
    const float* pb1 = (const float*)d_in[14];

    int nq = in_sizes[1] / 3;
    int E  = in_sizes[3];

    // ws layout: [agg nq*128 (path A)] [hist] [cursor] [start] [dsts] [srcs]
    size_t agg_bytes  = (size_t)nq * 128 * sizeof(float);
    size_t sort_bytes = 0;
    {
        size_t o = 0;
        o += ((size_t)nq * sizeof(int) + 15) & ~(size_t)15;
        o += ((size_t)nq * sizeof(int) + 15) & ~(size_t)15;
        o += ((size_t)(nq + 1) * sizeof(int) + 15) & ~(size_t)15;
        o += ((size_t)E * sizeof(int) + 15) & ~(size_t)15;
        o += ((size_t)E * sizeof(int) + 15) & ~(size_t)15;
        sort_bytes = o;
    }
    bool path_a = (agg_bytes + sort_bytes) <= ws_size;

    size_t off = path_a ? agg_bytes : 0;
    auto alloc = [&](size_t bytes) {
        void* p = (char*)d_ws + off;
        off += (bytes + 15) & ~(size_t)15;
        return p;
    };
    float* agg   = (float*)d_ws;  // path A only
    int* hist    = (int*)alloc((size_t)nq * sizeof(int));
    int* cursor  = (int*)alloc((size_t)nq * sizeof(int));
    int* start   = (int*)alloc((size_t)(nq + 1) * sizeof(int));
    int* dsts    = (int*)alloc((size_t)E * sizeof(int));
    int* srcs    = (int*)alloc((size_t)E * sizeof(int));

    size_t histpad = ((size_t)nq * sizeof(int) + 15) & ~(size_t)15;
    hipMemsetAsync(hist, 0, 2 * histpad, stream);

    hist_kernel<<<(E + 255) / 256, 256, 0, stream>>>(dst, hist, E);
    scan_kernel<<<1, 1024, 0, stream>>>(hist, start, nq);
    scatter_kernel<<<(E + 255) / 256, 256, 0, stream>>>(dst, src, start, cursor, dsts, srcs, E);

    constexpr int    QB   = 24;
    constexpr size_t SMEM = (size_t)(4352 + QB * 129) * 4;  // 29,792 B -> 5 blocks/CU
    int nb = (nq + QB - 1) / QB;

    if (path_a) {
        fused_kernel<QB, false><<<nb, BLOCK, SMEM, stream>>>(
            rndata, qpos, lpos, dsts, srcs, start,
            W0, b0, W1, b1, W2, b2, P0, pb0, P1, pb1, agg, nullptr, nq);
        proj_kernel<<<(nq + 255) / 256, 256, 0, stream>>>(
            agg, P0, pb0, P1, pb1, (float*)d_out, nq);
    } else {
        fused_kernel<QB, true><<<nb, BLOCK, SMEM, stream>>>(
            rndata, qpos, lpos, dsts, srcs, start,
            W0, b0, W1, b1, W2, b2, P0, pb0, P1, pb1, nullptr, (float*)d_out, nq);
    }
}